// Round 8
// baseline (127.366 us; speedup 1.0000x reference)
//
#include <hip/hip_runtime.h>
#include <hip/hip_cooperative_groups.h>
#include <math.h>

namespace cg = cooperative_groups;

#define B_ 8
#define C_ 64
#define N_ 4096
#define NT_ 32   // 128-wide n-tiles

// ws float offsets (shared by both paths)
#define SMP_OFF 0                          // SMp[tile][b][o]
#define SQP_OFF (NT_ * B_ * C_)            // SQp[tile][b][o]
#define SS_OFF  (SQP_OFF + NT_ * B_ * C_)  // sS[b]
#define SC_OFF  (SS_OFF + B_)              // sScale[b] = 1/(N*s+1)
#define A_OFF   (SC_OFF + B_)              // a[b][o]      (fallback)
#define BB_OFF  (A_OFF + B_ * C_)          // bb[b][o]     (fallback)
#define M_OFF   65536                      // M[b][o][n]   (fallback, 8 MB)

// ===========================================================================
// PRIMARY: single cooperative kernel. grid (32, 8) x 512 threads.
// tile==0 blocks additionally compute the per-batch scales before their work.
// __launch_bounds__(512, 4): VGPR cap 128 -> 2 blocks/CU -> coop grid of 256
// is guaranteed co-resident on 256 CUs.
// ===========================================================================
__global__ __launch_bounds__(512, 4) void k_fused(
        const float* __restrict__ x, const float* __restrict__ wvec,
        const float* __restrict__ conv_w, const float* __restrict__ conv_b,
        const float* __restrict__ gamma, const float* __restrict__ beta,
        float* __restrict__ ws, float* __restrict__ out) {
    cg::grid_group grid = cg::this_grid();
    const int tile = blockIdx.x;      // 0..31
    const int b    = blockIdx.y;
    const int t    = threadIdx.x;

    __shared__ float xsm[64 * 128];   // 32 KB: x-tile (ph1), stats (ph2)
    __shared__ float sred[8];

    const int n0 = tile * 128;
    const int o0 = (t >> 6) * 8;      // wave-uniform o-group
    const int nn = (t & 63) * 2;

    // ---- scales duty (tile==0 blocks only; block-uniform branch) ----
    if (tile == 0) {
        const float4* wb = reinterpret_cast<const float4*>(wvec + (size_t)b * N_);
        float p = 0.f;
        #pragma unroll
        for (int i = 0; i < 2; ++i) {
            const float4 v = wb[t + i * 512];
            const float vv[4] = {v.x, v.y, v.z, v.w};
            #pragma unroll
            for (int j = 0; j < 4; ++j)
                if (vv[j] > 0.f) { const float th = tanhf(vv[j]); p += th * th; }
        }
        #pragma unroll
        for (int m = 32; m >= 1; m >>= 1) p += __shfl_xor(p, m);
        if ((t & 63) == 0) sred[t >> 6] = p;
        __syncthreads();
        if (t == 0) {
            const float s = sred[0] + sred[1] + sred[2] + sred[3]
                          + sred[4] + sred[5] + sred[6] + sred[7];
            ws[SS_OFF + b] = s;
            ws[SC_OFF + b] = 1.f / ((float)N_ * s + 1.f);
        }
    }

    // ---- phase 1: M-tile in registers + per-tile partials ----
    const float* xb = x + (size_t)b * C_ * N_ + n0;
    const int k0 = (t & 31) * 4;
    #pragma unroll
    for (int it = 0; it < 4; ++it) {
        const int cc = it * 16 + (t >> 5);
        *reinterpret_cast<float4*>(&xsm[cc * 128 + k0]) =
            *reinterpret_cast<const float4*>(xb + (size_t)cc * N_ + k0);
    }
    __syncthreads();

    float a0[8], a1[8];
    #pragma unroll
    for (int i = 0; i < 8; ++i) { a0[i] = 0.f; a1[i] = 0.f; }
    #pragma unroll 4
    for (int c = 0; c < 64; ++c) {
        const float2 xv = *reinterpret_cast<const float2*>(&xsm[c * 128 + nn]);
        #pragma unroll
        for (int i = 0; i < 8; ++i) {
            const float wv = conv_w[(o0 + i) * 64 + c];   // wave-uniform -> s_load
            a0[i] += wv * xv.x;
            a1[i] += wv * xv.y;
        }
    }
    #pragma unroll
    for (int i = 0; i < 8; ++i) {
        float s = a0[i] + a1[i];
        float q = a0[i] * a0[i] + a1[i] * a1[i];
        #pragma unroll
        for (int m = 32; m >= 1; m >>= 1) {
            s += __shfl_xor(s, m);
            q += __shfl_xor(q, m);
        }
        if ((t & 63) == 0) {
            ws[SMP_OFF + (tile * B_ + b) * C_ + o0 + i] = s;
            ws[SQP_OFF + (tile * B_ + b) * C_ + o0 + i] = q;
        }
    }

    grid.sync();

    // ---- phase 2: redundant per-block BN stats (L2-hot 128 KB) ----
    float* sSM = xsm;                 // [8][64]
    float* sTs = xsm + 512;           // [8][64]
    float* sTq = xsm + 1024;          // [8][64]
    float* sAl = xsm + 1536;          // [64]
    float* sMe = xsm + 1600;          // [64]
    __syncthreads();                  // xsm reuse
    {
        const int b2 = t >> 6, o = t & 63;
        float SM = 0.f, SQ = 0.f;
        #pragma unroll 8
        for (int p2 = 0; p2 < NT_; ++p2) {
            SM += ws[SMP_OFF + (p2 * B_ + b2) * C_ + o];
            SQ += ws[SQP_OFF + (p2 * B_ + b2) * C_ + o];
        }
        const float sS2 = ws[SS_OFF + b2];
        const float sc2 = ws[SC_OFF + b2];
        const float q2  = sS2 * sc2 * SM + conv_b[o];
        sSM[b2 * 64 + o] = SM;
        sTs[b2 * 64 + o] = sc2 * SM + 4096.f * q2;
        sTq[b2 * 64 + o] = sc2 * sc2 * SQ + 2.f * sc2 * q2 * SM + 4096.f * q2 * q2;
    }
    __syncthreads();
    if (t < 64) {
        float Sy = 0.f, Syy = 0.f;
        #pragma unroll
        for (int b2 = 0; b2 < 8; ++b2) { Sy += sTs[b2 * 64 + t]; Syy += sTq[b2 * 64 + t]; }
        const float mean = Sy / 32768.f;
        const float var  = Syy / 32768.f - mean * mean;
        sAl[t] = gamma[t] * rsqrtf(var + 1e-5f);
        sMe[t] = mean;
    }
    __syncthreads();

    // ---- phase 3: apply affine + relu from registers ----
    const float sS = ws[SS_OFF + b];
    const float sc = ws[SC_OFF + b];
    #pragma unroll
    for (int i = 0; i < 8; ++i) {
        const int o = o0 + i;
        const float alpha = sAl[o];
        const float q  = sS * sc * sSM[b * 64 + o] + conv_b[o];
        const float av = sc * alpha;
        const float bv = (q - sMe[o]) * alpha + beta[o];
        float2 r;
        r.x = fmaxf(a0[i] * av + bv, 0.f);
        r.y = fmaxf(a1[i] * av + bv, 0.f);
        *reinterpret_cast<float2*>(out + ((size_t)(b * 64 + o)) * N_ + n0 + nn) = r;
    }
}

// ===========================================================================
// FALLBACK: proven 3-kernel path (r5, 85.7 us) — used only if the coop
// launch can't run. Identical math.
// ===========================================================================
__global__ __launch_bounds__(512) void k_conv(const float* __restrict__ x,
                                              const float* __restrict__ wvec,
                                              const float* __restrict__ conv_w,
                                              float* __restrict__ ws) {
    const int b = blockIdx.y;
    const int t = threadIdx.x;
    __shared__ float xsm[64 * 128];

    if (blockIdx.x == NT_) {
        const float4* wb = reinterpret_cast<const float4*>(wvec + (size_t)b * N_);
        float p = 0.f;
        #pragma unroll
        for (int i = 0; i < 2; ++i) {
            const float4 v = wb[t + i * 512];
            const float vv[4] = {v.x, v.y, v.z, v.w};
            #pragma unroll
            for (int j = 0; j < 4; ++j)
                if (vv[j] > 0.f) { const float th = tanhf(vv[j]); p += th * th; }
        }
        #pragma unroll
        for (int m = 32; m >= 1; m >>= 1) p += __shfl_xor(p, m);
        if ((t & 63) == 0) xsm[t >> 6] = p;
        __syncthreads();
        if (t == 0) {
            const float s = xsm[0] + xsm[1] + xsm[2] + xsm[3]
                          + xsm[4] + xsm[5] + xsm[6] + xsm[7];
            ws[SS_OFF + b] = s;
            ws[SC_OFF + b] = 1.f / ((float)N_ * s + 1.f);
        }
        return;
    }

    const int tile = blockIdx.x;
    const int n0 = tile * 128;
    const float* xb = x + (size_t)b * C_ * N_ + n0;
    const int k0 = (t & 31) * 4;
    #pragma unroll
    for (int it = 0; it < 4; ++it) {
        const int cc = it * 16 + (t >> 5);
        *reinterpret_cast<float4*>(&xsm[cc * 128 + k0]) =
            *reinterpret_cast<const float4*>(xb + (size_t)cc * N_ + k0);
    }
    __syncthreads();

    const int o0 = (t >> 6) * 8;
    const int nn = (t & 63) * 2;
    float a0[8], a1[8];
    #pragma unroll
    for (int i = 0; i < 8; ++i) { a0[i] = 0.f; a1[i] = 0.f; }
    #pragma unroll 4
    for (int c = 0; c < 64; ++c) {
        const float2 xv = *reinterpret_cast<const float2*>(&xsm[c * 128 + nn]);
        #pragma unroll
        for (int i = 0; i < 8; ++i) {
            const float wv = conv_w[(o0 + i) * 64 + c];
            a0[i] += wv * xv.x;
            a1[i] += wv * xv.y;
        }
    }
    #pragma unroll
    for (int i = 0; i < 8; ++i) {
        const int o = o0 + i;
        *reinterpret_cast<float2*>(ws + M_OFF + ((size_t)(b * 64 + o)) * N_ + n0 + nn) =
            make_float2(a0[i], a1[i]);
        float s = a0[i] + a1[i];
        float q = a0[i] * a0[i] + a1[i] * a1[i];
        #pragma unroll
        for (int m = 32; m >= 1; m >>= 1) {
            s += __shfl_xor(s, m);
            q += __shfl_xor(q, m);
        }
        if ((t & 63) == 0) {
            ws[SMP_OFF + (tile * B_ + b) * C_ + o] = s;
            ws[SQP_OFF + (tile * B_ + b) * C_ + o] = q;
        }
    }
}

__global__ __launch_bounds__(512) void k_stats(const float* __restrict__ conv_b,
                                               const float* __restrict__ gamma,
                                               const float* __restrict__ beta,
                                               float* __restrict__ ws) {
    const int t = threadIdx.x;
    const int b = t >> 6, o = t & 63;
    __shared__ float sTs[8][64], sTq[8][64];
    __shared__ float sAl[64], sMe[64];

    float SM = 0.f, SQ = 0.f;
    #pragma unroll 8
    for (int p = 0; p < NT_; ++p) {
        SM += ws[SMP_OFF + (p * B_ + b) * C_ + o];
        SQ += ws[SQP_OFF + (p * B_ + b) * C_ + o];
    }
    const float sS = ws[SS_OFF + b];
    const float sc = ws[SC_OFF + b];
    const float q  = sS * sc * SM + conv_b[o];
    sTs[b][o] = sc * SM + 4096.f * q;
    sTq[b][o] = sc * sc * SQ + 2.f * sc * q * SM + 4096.f * q * q;
    __syncthreads();
    if (t < 64) {
        float Sy = 0.f, Syy = 0.f;
        #pragma unroll
        for (int b2 = 0; b2 < 8; ++b2) { Sy += sTs[b2][t]; Syy += sTq[b2][t]; }
        const float mean = Sy / 32768.f;
        const float var  = Syy / 32768.f - mean * mean;
        sAl[t] = gamma[t] * rsqrtf(var + 1e-5f);
        sMe[t] = mean;
    }
    __syncthreads();
    const float alpha = sAl[o];
    ws[A_OFF  + b * 64 + o] = sc * alpha;
    ws[BB_OFF + b * 64 + o] = (q - sMe[o]) * alpha + beta[o];
}

__global__ __launch_bounds__(256) void k_emit(const float* __restrict__ ws,
                                              float* __restrict__ out) {
    const int idx = blockIdx.x * 256 + threadIdx.x;
    #pragma unroll
    for (int h = 0; h < 2; ++h) {
        const int e = idx + h * (1024 * 256);
        const int row = e >> 10;
        const float a  = ws[A_OFF + row];
        const float bb = ws[BB_OFF + row];
        const float4 m = *reinterpret_cast<const float4*>(ws + M_OFF + (size_t)e * 4);
        float4 r;
        r.x = fmaxf(m.x * a + bb, 0.f);
        r.y = fmaxf(m.y * a + bb, 0.f);
        r.z = fmaxf(m.z * a + bb, 0.f);
        r.w = fmaxf(m.w * a + bb, 0.f);
        *reinterpret_cast<float4*>(out + (size_t)e * 4) = r;
    }
}

extern "C" void kernel_launch(void* const* d_in, const int* in_sizes, int n_in,
                              void* d_out, int out_size, void* d_ws, size_t ws_size,
                              hipStream_t stream) {
    (void)in_sizes; (void)n_in; (void)out_size; (void)ws_size;
    const float* x      = (const float*)d_in[0];
    const float* w      = (const float*)d_in[1];
    const float* conv_w = (const float*)d_in[2];
    const float* conv_b = (const float*)d_in[3];
    const float* gamma  = (const float*)d_in[4];
    const float* beta   = (const float*)d_in[5];
    float* out = (float*)d_out;
    float* ws  = (float*)d_ws;

    // co-residency check (host-side queries; deterministic per device)
    int dev = 0, nCU = 0, maxb = 0;
    hipGetDevice(&dev);
    hipDeviceGetAttribute(&nCU, hipDeviceAttributeMultiprocessorCount, dev);
    bool coop = (hipOccupancyMaxActiveBlocksPerMultiprocessor(
                     &maxb, (const void*)k_fused, 512, 0) == hipSuccess) &&
                (maxb * nCU >= NT_ * B_);

    if (coop) {
        void* args[] = {(void*)&x, (void*)&w, (void*)&conv_w, (void*)&conv_b,
                        (void*)&gamma, (void*)&beta, (void*)&ws, (void*)&out};
        coop = (hipLaunchCooperativeKernel((const void*)k_fused, dim3(NT_, B_),
                                           dim3(512), args, 0, stream) == hipSuccess);
    }
    if (!coop) {
        k_conv<<<dim3(NT_ + 1, B_), 512, 0, stream>>>(x, w, conv_w, ws);
        k_stats<<<1, 512, 0, stream>>>(conv_b, gamma, beta, ws);
        k_emit<<<1024, 256, 0, stream>>>(ws, out);
    }
}

// Round 11
// 90.524 us; speedup vs baseline: 1.4070x; 1.4070x over previous
//
#include <hip/hip_runtime.h>
#include <math.h>

#define B_ 8
#define C_ 64
#define N_ 4096
#define NT_ 32   // 128-wide n-tiles

// ws float offsets (tiny scratch only; M is never materialized)
#define SMP_OFF 0                          // SMp[tile][b][o]
#define SQP_OFF (NT_ * B_ * C_)            // SQp[tile][b][o]
#define SS_OFF  (SQP_OFF + NT_ * B_ * C_)  // sS[b] = sum relu(tanh(w))^2
#define SC_OFF  (SS_OFF + B_)              // sScale[b] = 1/(N*s+1)

// ---------------------------------------------------------------------------
// K1: per-tile partials SM = sum_n M, SQ = sum_n M^2 (M in registers only).
// grid (32, 8) x 512 threads; tile==0 blocks also compute per-batch scales.
// ---------------------------------------------------------------------------
__global__ __launch_bounds__(512) void k_part(const float* __restrict__ x,
                                              const float* __restrict__ wvec,
                                              const float* __restrict__ conv_w,
                                              float* __restrict__ ws) {
    const int tile = blockIdx.x;
    const int b    = blockIdx.y;
    const int t    = threadIdx.x;

    __shared__ float xsm[64 * 128];   // [c][n] 32 KB
    __shared__ float sred[8];

    if (tile == 0) {                  // block-uniform: scales duty
        const float4* wb = reinterpret_cast<const float4*>(wvec + (size_t)b * N_);
        float p = 0.f;
        #pragma unroll
        for (int i = 0; i < 2; ++i) {
            const float4 v = wb[t + i * 512];
            const float vv[4] = {v.x, v.y, v.z, v.w};
            #pragma unroll
            for (int j = 0; j < 4; ++j)
                if (vv[j] > 0.f) { const float th = tanhf(vv[j]); p += th * th; }
        }
        #pragma unroll
        for (int m = 32; m >= 1; m >>= 1) p += __shfl_xor(p, m);
        if ((t & 63) == 0) sred[t >> 6] = p;
        __syncthreads();
        if (t == 0) {
            const float s = sred[0] + sred[1] + sred[2] + sred[3]
                          + sred[4] + sred[5] + sred[6] + sred[7];
            ws[SS_OFF + b] = s;
            ws[SC_OFF + b] = 1.f / ((float)N_ * s + 1.f);
        }
    }

    const int n0 = tile * 128;
    const float* xb = x + (size_t)b * C_ * N_ + n0;
    const int k0 = (t & 31) * 4;
    #pragma unroll
    for (int it = 0; it < 4; ++it) {
        const int cc = it * 16 + (t >> 5);
        *reinterpret_cast<float4*>(&xsm[cc * 128 + k0]) =
            *reinterpret_cast<const float4*>(xb + (size_t)cc * N_ + k0);
    }
    __syncthreads();

    const int o0 = (t >> 6) * 8;      // wave-uniform o-group
    const int nn = (t & 63) * 2;
    float a0[8], a1[8];
    #pragma unroll
    for (int i = 0; i < 8; ++i) { a0[i] = 0.f; a1[i] = 0.f; }
    #pragma unroll 4
    for (int c = 0; c < 64; ++c) {
        const float2 xv = *reinterpret_cast<const float2*>(&xsm[c * 128 + nn]);
        #pragma unroll
        for (int i = 0; i < 8; ++i) {
            const float wv = conv_w[(o0 + i) * 64 + c];   // wave-uniform -> s_load
            a0[i] += wv * xv.x;
            a1[i] += wv * xv.y;
        }
    }
    #pragma unroll
    for (int i = 0; i < 8; ++i) {
        float s = a0[i] + a1[i];
        float q = a0[i] * a0[i] + a1[i] * a1[i];
        #pragma unroll
        for (int m = 32; m >= 1; m >>= 1) {
            s += __shfl_xor(s, m);
            q += __shfl_xor(q, m);
        }
        if ((t & 63) == 0) {
            ws[SMP_OFF + (tile * B_ + b) * C_ + o0 + i] = s;
            ws[SQP_OFF + (tile * B_ + b) * C_ + o0 + i] = q;
        }
    }
}

// ---------------------------------------------------------------------------
// K2: per-block redundant BN stats (128 KB partials, L2-hot) + recompute M
// from x (L2-hot, same grid mapping as K1) + emit relu(av*M + bv).
// grid (32, 8) x 512 threads.
// ---------------------------------------------------------------------------
__global__ __launch_bounds__(512) void k_emit(const float* __restrict__ x,
                                              const float* __restrict__ conv_w,
                                              const float* __restrict__ conv_b,
                                              const float* __restrict__ gamma,
                                              const float* __restrict__ beta,
                                              const float* __restrict__ ws,
                                              float* __restrict__ out) {
    const int tile = blockIdx.x;
    const int b    = blockIdx.y;
    const int t    = threadIdx.x;

    __shared__ float xsm[64 * 128];   // 32 KB x-tile
    __shared__ float sSM[512], sTs[512], sTq[512];
    __shared__ float sAl[64], sMe[64];

    // stage x tile (issue first; stats below hides the latency)
    const int n0 = tile * 128;
    const float* xb = x + (size_t)b * C_ * N_ + n0;
    const int k0 = (t & 31) * 4;
    #pragma unroll
    for (int it = 0; it < 4; ++it) {
        const int cc = it * 16 + (t >> 5);
        *reinterpret_cast<float4*>(&xsm[cc * 128 + k0]) =
            *reinterpret_cast<const float4*>(xb + (size_t)cc * N_ + k0);
    }

    // stats from partials (independent of x staging)
    {
        const int b2 = t >> 6, o = t & 63;
        float SM = 0.f, SQ = 0.f;
        #pragma unroll 8
        for (int p2 = 0; p2 < NT_; ++p2) {
            SM += ws[SMP_OFF + (p2 * B_ + b2) * C_ + o];
            SQ += ws[SQP_OFF + (p2 * B_ + b2) * C_ + o];
        }
        const float sS2 = ws[SS_OFF + b2];
        const float sc2 = ws[SC_OFF + b2];
        const float q2  = sS2 * sc2 * SM + conv_b[o];
        sSM[b2 * 64 + o] = SM;
        sTs[b2 * 64 + o] = sc2 * SM + 4096.f * q2;
        sTq[b2 * 64 + o] = sc2 * sc2 * SQ + 2.f * sc2 * q2 * SM + 4096.f * q2 * q2;
    }
    __syncthreads();
    if (t < 64) {
        float Sy = 0.f, Syy = 0.f;
        #pragma unroll
        for (int b2 = 0; b2 < 8; ++b2) { Sy += sTs[b2 * 64 + t]; Syy += sTq[b2 * 64 + t]; }
        const float mean = Sy / 32768.f;
        const float var  = Syy / 32768.f - mean * mean;
        sAl[t] = gamma[t] * rsqrtf(var + 1e-5f);
        sMe[t] = mean;
    }
    __syncthreads();

    // recompute M from xsm and emit
    const int o0 = (t >> 6) * 8;
    const int nn = (t & 63) * 2;
    float a0[8], a1[8];
    #pragma unroll
    for (int i = 0; i < 8; ++i) { a0[i] = 0.f; a1[i] = 0.f; }
    #pragma unroll 4
    for (int c = 0; c < 64; ++c) {
        const float2 xv = *reinterpret_cast<const float2*>(&xsm[c * 128 + nn]);
        #pragma unroll
        for (int i = 0; i < 8; ++i) {
            const float wv = conv_w[(o0 + i) * 64 + c];
            a0[i] += wv * xv.x;
            a1[i] += wv * xv.y;
        }
    }
    const float sS = ws[SS_OFF + b];
    const float sc = ws[SC_OFF + b];
    #pragma unroll
    for (int i = 0; i < 8; ++i) {
        const int o = o0 + i;
        const float alpha = sAl[o];
        const float q  = sS * sc * sSM[b * 64 + o] + conv_b[o];
        const float av = sc * alpha;
        const float bv = (q - sMe[o]) * alpha + beta[o];
        float2 r;
        r.x = fmaxf(a0[i] * av + bv, 0.f);
        r.y = fmaxf(a1[i] * av + bv, 0.f);
        *reinterpret_cast<float2*>(out + ((size_t)(b * 64 + o)) * N_ + n0 + nn) = r;
    }
}

extern "C" void kernel_launch(void* const* d_in, const int* in_sizes, int n_in,
                              void* d_out, int out_size, void* d_ws, size_t ws_size,
                              hipStream_t stream) {
    (void)in_sizes; (void)n_in; (void)out_size; (void)ws_size;
    const float* x      = (const float*)d_in[0];
    const float* w      = (const float*)d_in[1];
    const float* conv_w = (const float*)d_in[2];
    const float* conv_b = (const float*)d_in[3];
    const float* gamma  = (const float*)d_in[4];
    const float* beta   = (const float*)d_in[5];
    float* out = (float*)d_out;
    float* ws  = (float*)d_ws;

    k_part<<<dim3(NT_, B_), 512, 0, stream>>>(x, w, conv_w, ws);
    k_emit<<<dim3(NT_, B_), 512, 0, stream>>>(x, conv_w, conv_b, gamma, beta, ws, out);
}

// Round 12
// 87.101 us; speedup vs baseline: 1.4623x; 1.0393x over previous
//
#include <hip/hip_runtime.h>
#include <math.h>

#define B_ 8
#define C_ 64
#define N_ 4096
#define NT_ 32   // 128-wide n-tiles

// ws float offsets
#define SMP_OFF 0                          // SMp[tile][b][o]
#define SQP_OFF (NT_ * B_ * C_)            // SQp[tile][b][o]
#define SS_OFF  (SQP_OFF + NT_ * B_ * C_)  // sS[b] = sum relu(tanh(w))^2
#define SC_OFF  (SS_OFF + B_)              // sScale[b] = 1/(N*s+1)
#define M_OFF   65536                      // M[b][o][n] (8.4 MB)

// ---------------------------------------------------------------------------
// K1: M = W x (written to ws) + per-tile partials SM/SQ.
// grid (32, 8) x 512 threads; tile==0 blocks also do the per-batch scales.
// Same grid shape as K2 -> same linear-ID->XCD mapping -> M stays L2-local.
// ---------------------------------------------------------------------------
__global__ __launch_bounds__(512) void k_conv(const float* __restrict__ x,
                                              const float* __restrict__ wvec,
                                              const float* __restrict__ conv_w,
                                              float* __restrict__ ws) {
    const int tile = blockIdx.x;
    const int b    = blockIdx.y;
    const int t    = threadIdx.x;

    __shared__ float xsm[64 * 128];   // [c][n] 32 KB
    __shared__ float sred[8];

    if (tile == 0) {                  // block-uniform: scales duty
        const float4* wb = reinterpret_cast<const float4*>(wvec + (size_t)b * N_);
        float p = 0.f;
        #pragma unroll
        for (int i = 0; i < 2; ++i) {
            const float4 v = wb[t + i * 512];
            const float vv[4] = {v.x, v.y, v.z, v.w};
            #pragma unroll
            for (int j = 0; j < 4; ++j)
                if (vv[j] > 0.f) { const float th = tanhf(vv[j]); p += th * th; }
        }
        #pragma unroll
        for (int m = 32; m >= 1; m >>= 1) p += __shfl_xor(p, m);
        if ((t & 63) == 0) sred[t >> 6] = p;
        __syncthreads();
        if (t == 0) {
            const float s = sred[0] + sred[1] + sred[2] + sred[3]
                          + sred[4] + sred[5] + sred[6] + sred[7];
            ws[SS_OFF + b] = s;
            ws[SC_OFF + b] = 1.f / ((float)N_ * s + 1.f);
        }
    }

    const int n0 = tile * 128;
    const float* xb = x + (size_t)b * C_ * N_ + n0;
    const int k0 = (t & 31) * 4;
    #pragma unroll
    for (int it = 0; it < 4; ++it) {
        const int cc = it * 16 + (t >> 5);
        *reinterpret_cast<float4*>(&xsm[cc * 128 + k0]) =
            *reinterpret_cast<const float4*>(xb + (size_t)cc * N_ + k0);
    }
    __syncthreads();

    const int o0 = (t >> 6) * 8;      // wave-uniform o-group
    const int nn = (t & 63) * 2;
    float a0[8], a1[8];
    #pragma unroll
    for (int i = 0; i < 8; ++i) { a0[i] = 0.f; a1[i] = 0.f; }
    #pragma unroll 4
    for (int c = 0; c < 64; ++c) {
        const float2 xv = *reinterpret_cast<const float2*>(&xsm[c * 128 + nn]);
        #pragma unroll
        for (int i = 0; i < 8; ++i) {
            const float wv = conv_w[(o0 + i) * 64 + c];   // wave-uniform -> s_load
            a0[i] += wv * xv.x;
            a1[i] += wv * xv.y;
        }
    }
    #pragma unroll
    for (int i = 0; i < 8; ++i) {
        const int o = o0 + i;
        *reinterpret_cast<float2*>(ws + M_OFF + ((size_t)(b * 64 + o)) * N_ + n0 + nn) =
            make_float2(a0[i], a1[i]);
        float s = a0[i] + a1[i];
        float q = a0[i] * a0[i] + a1[i] * a1[i];
        #pragma unroll
        for (int m = 32; m >= 1; m >>= 1) {
            s += __shfl_xor(s, m);
            q += __shfl_xor(q, m);
        }
        if ((t & 63) == 0) {
            ws[SMP_OFF + (tile * B_ + b) * C_ + o] = s;
            ws[SQP_OFF + (tile * B_ + b) * C_ + o] = q;
        }
    }
}

// ---------------------------------------------------------------------------
// K2: fused stats + emit. grid (32, 8) x 512 threads (same mapping as K1).
// Issues its 8 M-loads first (latency hidden under the stats reduce), then
// redundant per-block stats from the 128 KB partials (L2-hot), then applies
// relu(av*M + bv) and stores.
// ---------------------------------------------------------------------------
__global__ __launch_bounds__(512) void k_emit(const float* __restrict__ conv_b,
                                              const float* __restrict__ gamma,
                                              const float* __restrict__ beta,
                                              const float* __restrict__ ws,
                                              float* __restrict__ out) {
    const int tile = blockIdx.x;
    const int b    = blockIdx.y;
    const int t    = threadIdx.x;

    __shared__ float sSM[512], sTs[512], sTq[512];
    __shared__ float sAl[64], sMe[64];

    const int n0 = tile * 128;
    const int o0 = (t >> 6) * 8;
    const int nn = (t & 63) * 2;

    // issue M loads first (independent of stats; vmcnt waited at apply time)
    float2 mv[8];
    #pragma unroll
    for (int i = 0; i < 8; ++i)
        mv[i] = *reinterpret_cast<const float2*>(
            ws + M_OFF + ((size_t)(b * 64 + o0 + i)) * N_ + n0 + nn);

    // stats from partials
    {
        const int b2 = t >> 6, o = t & 63;
        float SM = 0.f, SQ = 0.f;
        #pragma unroll
        for (int p2 = 0; p2 < NT_; ++p2) {
            SM += ws[SMP_OFF + (p2 * B_ + b2) * C_ + o];
            SQ += ws[SQP_OFF + (p2 * B_ + b2) * C_ + o];
        }
        const float sS2 = ws[SS_OFF + b2];
        const float sc2 = ws[SC_OFF + b2];
        const float q2  = sS2 * sc2 * SM + conv_b[o];
        sSM[b2 * 64 + o] = SM;
        sTs[b2 * 64 + o] = sc2 * SM + 4096.f * q2;
        sTq[b2 * 64 + o] = sc2 * sc2 * SQ + 2.f * sc2 * q2 * SM + 4096.f * q2 * q2;
    }
    __syncthreads();
    if (t < 64) {
        float Sy = 0.f, Syy = 0.f;
        #pragma unroll
        for (int b2 = 0; b2 < 8; ++b2) { Sy += sTs[b2 * 64 + t]; Syy += sTq[b2 * 64 + t]; }
        const float mean = Sy / 32768.f;
        const float var  = Syy / 32768.f - mean * mean;
        sAl[t] = gamma[t] * rsqrtf(var + 1e-5f);
        sMe[t] = mean;
    }
    __syncthreads();

    const float sS = ws[SS_OFF + b];
    const float sc = ws[SC_OFF + b];
    #pragma unroll
    for (int i = 0; i < 8; ++i) {
        const int o = o0 + i;
        const float alpha = sAl[o];
        const float q  = sS * sc * sSM[b * 64 + o] + conv_b[o];
        const float av = sc * alpha;
        const float bv = (q - sMe[o]) * alpha + beta[o];
        float2 r;
        r.x = fmaxf(mv[i].x * av + bv, 0.f);
        r.y = fmaxf(mv[i].y * av + bv, 0.f);
        *reinterpret_cast<float2*>(out + ((size_t)(b * 64 + o)) * N_ + n0 + nn) = r;
    }
}

extern "C" void kernel_launch(void* const* d_in, const int* in_sizes, int n_in,
                              void* d_out, int out_size, void* d_ws, size_t ws_size,
                              hipStream_t stream) {
    (void)in_sizes; (void)n_in; (void)out_size; (void)ws_size;
    const float* x      = (const float*)d_in[0];
    const float* w      = (const float*)d_in[1];
    const float* conv_w = (const float*)d_in[2];
    const float* conv_b = (const float*)d_in[3];
    const float* gamma  = (const float*)d_in[4];
    const float* beta   = (const float*)d_in[5];
    float* out = (float*)d_out;
    float* ws  = (float*)d_ws;

    k_conv<<<dim3(NT_, B_), 512, 0, stream>>>(x, w, conv_w, ws);
    k_emit<<<dim3(NT_, B_), 512, 0, stream>>>(conv_b, gamma, beta, ws, out);
}